// Round 1
// baseline (134.816 us; speedup 1.0000x reference)
//
#include <hip/hip_runtime.h>
#include <math.h>

#define NN 100000   // N
#define NF 10       // n features
#define MC 8        // M_CLUSTERS
#define KK 16       // K neighbours
#define BB 4        // batch
#define MUF 20.0f

// ---------------- Kernel 1: enc[b,c] = sum_j x[b,j] * W_enc[c,j] ----------------
// 320 blocks: 40 (b,c) pairs x 8 K-slices. atomicAdd into zeroed enc buffer.
__global__ __launch_bounds__(256) void k_enc(const float* __restrict__ x,
                                             const float* __restrict__ Wenc,
                                             float* __restrict__ enc) {
    int blk = blockIdx.x;          // 0..319
    int pair = blk >> 3;           // 0..39
    int slice = blk & 7;           // 0..7
    int b = pair / NF, c = pair % NF;
    const int chunk = (NN + 7) / 8;          // 12500
    int j0 = slice * chunk;
    int j1 = j0 + chunk; if (j1 > NN) j1 = NN;
    const float* xp = x + (size_t)b * NN;
    const float* wp = Wenc + (size_t)c * NN;
    float acc = 0.f;
    for (int j = j0 + threadIdx.x; j < j1; j += blockDim.x)
        acc += xp[j] * wp[j];
    // wave64 reduce
    for (int off = 32; off; off >>= 1) acc += __shfl_down(acc, off);
    __shared__ float red[4];
    int wave = threadIdx.x >> 6;
    if ((threadIdx.x & 63) == 0) red[wave] = acc;
    __syncthreads();
    if (threadIdx.x == 0) {
        float s = red[0] + red[1] + red[2] + red[3];
        atomicAdd(&enc[b * NF + c], s);
    }
}

// ---------------- Kernel 2: dinv[b, c*8+m] = 1 / ((bw*MU)^2) ----------------
// bw = (1/60 - lo) * sigmoid(enc @ W_bw.T) + lo,  lo = 4/60/MU
__global__ void k_bw(const float* __restrict__ enc, const float* __restrict__ Wbw,
                     float* __restrict__ dinv) {
    int t = threadIdx.x;                    // 0..319
    if (t >= BB * NF * MC) return;
    int b = t / (NF * MC);
    int r = t % (NF * MC);                  // r = c*MC + m
    float z = 0.f;
#pragma unroll
    for (int c = 0; c < NF; ++c) z += enc[b * NF + c] * Wbw[r * NF + c];
    float sig = 1.f / (1.f + expf(-z));
    const float lo = (float)(4.0 / 60.0 / 20.0);
    const float sc = (float)(1.0 / 60.0 - 4.0 / 60.0 / 20.0);
    float bw = sc * sig + lo;
    float v = bw * MUF;
    dinv[t] = 1.0f / (v * v);
}

// ---------------- Kernel 3: transpose W_dec (n,N) -> Wt (N,16) padded ----------------
__global__ __launch_bounds__(256) void k_tr(const float* __restrict__ Wdec,
                                            float* __restrict__ Wt) {
    int j = blockIdx.x * blockDim.x + threadIdx.x;
    if (j >= NN) return;
    float tmp[12];
#pragma unroll
    for (int c = 0; c < NF; ++c) tmp[c] = Wdec[(size_t)c * NN + j];
    tmp[10] = 0.f; tmp[11] = 0.f;
    float* o = Wt + (size_t)j * 16;
#pragma unroll
    for (int c = 0; c < 12; ++c) o[c] = tmp[c];
}

// ---------------- Kernel 4: fused window/normalize/smooth/project ----------------
// thread t -> j = t>>2, b = t&3. Per thread: 10 (c) accumulator pairs.
template <bool TR>
__global__ __launch_bounds__(256) void k_main(const float* __restrict__ ndist,
                                              const int* __restrict__ nbid,
                                              const int* __restrict__ labels,
                                              const float* __restrict__ dinvbuf,
                                              const float* __restrict__ encbuf,
                                              const float* __restrict__ Wsrc,
                                              float* __restrict__ out) {
    __shared__ float s_dinv[BB * NF * MC];   // 320
    __shared__ float s_enc[BB * NF];         // 40
    for (int i = threadIdx.x; i < BB * NF * MC; i += blockDim.x)
        s_dinv[i] = dinvbuf[i];
    if (threadIdx.x < BB * NF) s_enc[threadIdx.x] = encbuf[threadIdx.x];
    __syncthreads();

    int t = blockIdx.x * blockDim.x + threadIdx.x;
    int j = t >> 2, b = t & 3;
    if (j >= NN) return;

    int lab = labels[j];
    float dinv[NF];
#pragma unroll
    for (int c = 0; c < NF; ++c)
        dinv[c] = s_dinv[b * (NF * MC) + c * MC + lab];

    // distances (squared on the fly) and neighbour ids, 64B aligned rows
    const float4* dp = (const float4*)(ndist + (size_t)j * KK);
    float4 dv0 = dp[0], dv1 = dp[1], dv2 = dp[2], dv3 = dp[3];
    float nd[KK] = {dv0.x, dv0.y, dv0.z, dv0.w, dv1.x, dv1.y, dv1.z, dv1.w,
                    dv2.x, dv2.y, dv2.z, dv2.w, dv3.x, dv3.y, dv3.z, dv3.w};
    const int4* np = (const int4*)(nbid + (size_t)j * KK);
    int4 nv0 = np[0], nv1 = np[1], nv2 = np[2], nv3 = np[3];
    int nb[KK] = {nv0.x, nv0.y, nv0.z, nv0.w, nv1.x, nv1.y, nv1.z, nv1.w,
                  nv2.x, nv2.y, nv2.z, nv2.w, nv3.x, nv3.y, nv3.z, nv3.w};

    float wsum[NF], sm[NF];
#pragma unroll
    for (int c = 0; c < NF; ++c) { wsum[c] = 0.f; sm[c] = 0.f; }

#pragma unroll
    for (int k = 0; k < KK; ++k) {
        float d = nd[k];
        float dd = d * d;
        float bas[12];
        if (TR) {
            const float4* bp = (const float4*)(Wsrc + (size_t)nb[k] * 16);
            float4 b0 = bp[0], b1 = bp[1], b2 = bp[2];
            bas[0] = b0.x; bas[1] = b0.y; bas[2] = b0.z; bas[3] = b0.w;
            bas[4] = b1.x; bas[5] = b1.y; bas[6] = b1.z; bas[7] = b1.w;
            bas[8] = b2.x; bas[9] = b2.y; bas[10] = b2.z; bas[11] = b2.w;
        } else {
#pragma unroll
            for (int c = 0; c < NF; ++c) bas[c] = Wsrc[(size_t)c * NN + nb[k]];
        }
#pragma unroll
        for (int c = 0; c < NF; ++c) {
            float w = fmaf(-dd, dinv[c], 1.0f);
            w = fmaxf(w, 0.f);
            wsum[c] += w;
            sm[c] = fmaf(w, bas[c], sm[c]);
        }
    }

    float acc = 0.f;
#pragma unroll
    for (int c = 0; c < NF; ++c)
        acc += s_enc[b * NF + c] * (sm[c] / wsum[c]);
    out[(size_t)b * NN + j] = acc;
}

extern "C" void kernel_launch(void* const* d_in, const int* in_sizes, int n_in,
                              void* d_out, int out_size, void* d_ws, size_t ws_size,
                              hipStream_t stream) {
    const float* x      = (const float*)d_in[0];
    const float* Wenc   = (const float*)d_in[1];
    const float* Wdec   = (const float*)d_in[2];
    const float* Wbw    = (const float*)d_in[3];
    const float* ndist  = (const float*)d_in[4];
    const int*   nbid   = (const int*)d_in[5];
    const int*   labels = (const int*)d_in[6];
    float* out = (float*)d_out;

    float* enc  = (float*)d_ws;                        // 40 floats
    float* dinv = (float*)((char*)d_ws + 256);         // 320 floats
    float* Wt   = (float*)((char*)d_ws + 4096);        // N*16 floats (6.4 MB)
    size_t need = 4096 + (size_t)NN * 16 * sizeof(float);
    bool tr = (ws_size >= need);

    hipMemsetAsync(d_ws, 0, BB * NF * sizeof(float), stream);   // zero enc accumulators
    k_enc<<<320, 256, 0, stream>>>(x, Wenc, enc);
    k_bw<<<1, 320, 0, stream>>>(enc, Wbw, dinv);
    if (tr) k_tr<<<(NN + 255) / 256, 256, 0, stream>>>(Wdec, Wt);

    int blocks = (NN * BB + 255) / 256;
    if (tr)
        k_main<true><<<blocks, 256, 0, stream>>>(ndist, nbid, labels, dinv, enc, Wt, out);
    else
        k_main<false><<<blocks, 256, 0, stream>>>(ndist, nbid, labels, dinv, enc, Wdec, out);
}

// Round 3
// 112.745 us; speedup vs baseline: 1.1958x; 1.1958x over previous
//
#include <hip/hip_runtime.h>
#include <math.h>

#define NN 100000   // N
#define NF 10       // n features
#define MC 8        // M_CLUSTERS
#define KK 16       // K neighbours
#define BB 4        // batch
#define MUF 20.0f

#define ENC_SLICES 32
#define ENC_BLOCKS (BB * NF * ENC_SLICES)   // 1280
#define TR_BLOCKS  ((NN + 255) / 256)       // 391

__device__ __forceinline__ float frcp(float x) {
#if __has_builtin(__builtin_amdgcn_rcpf)
    return __builtin_amdgcn_rcpf(x);   // v_rcp_f32, ~1 ulp; wsum >= 7 so safe
#else
    return 1.0f / x;
#endif
}

// ---------------- Kernel A: enc partial sums + W_dec transpose, one launch ----
// blocks [0, 1280): pair = blk>>5 (b*10+c), slice = blk&31 -> part[blk]
// blocks [1280, 1280+391): transpose W_dec (n,N) -> Wt (N,16) 64B rows
template <bool TR>
__global__ __launch_bounds__(256) void k_prep(const float* __restrict__ x,
                                              const float* __restrict__ Wenc,
                                              const float* __restrict__ Wdec,
                                              float* __restrict__ part,
                                              float* __restrict__ Wt) {
    int blk = blockIdx.x;
    if (blk < ENC_BLOCKS) {
        int pair  = blk >> 5;
        int slice = blk & 31;
        int b = pair / NF, c = pair % NF;
        const int chunk = NN / ENC_SLICES;   // 3125
        int j0 = slice * chunk;
        int j1 = j0 + chunk;
        const float* xp = x + (size_t)b * NN;
        const float* wp = Wenc + (size_t)c * NN;
        float acc = 0.f;
        for (int j = j0 + threadIdx.x; j < j1; j += 256)
            acc = fmaf(xp[j], wp[j], acc);
#pragma unroll
        for (int off = 32; off; off >>= 1) acc += __shfl_down(acc, off);
        __shared__ float red[4];
        if ((threadIdx.x & 63) == 0) red[threadIdx.x >> 6] = acc;
        __syncthreads();
        if (threadIdx.x == 0) part[blk] = red[0] + red[1] + red[2] + red[3];
    } else if (TR) {
        int j = (blk - ENC_BLOCKS) * 256 + threadIdx.x;
        if (j < NN) {
            float tmp[16];
#pragma unroll
            for (int c = 0; c < NF; ++c) tmp[c] = Wdec[(size_t)c * NN + j];
#pragma unroll
            for (int c = NF; c < 16; ++c) tmp[c] = 0.f;
            float4* o = (float4*)(Wt + (size_t)j * 16);
            o[0] = make_float4(tmp[0], tmp[1], tmp[2], tmp[3]);
            o[1] = make_float4(tmp[4], tmp[5], tmp[6], tmp[7]);
            o[2] = make_float4(tmp[8], tmp[9], tmp[10], tmp[11]);
            o[3] = make_float4(tmp[12], tmp[13], tmp[14], tmp[15]);
        }
    }
}

// ---------------- Kernel B: prologue (enc + dinv in LDS) + fused main --------
// thread g: j = g>>1, handles b = {bh, bh+1} where bh = (g&1)*2.
template <bool TR>
__global__ __launch_bounds__(256) void k_main(const float* __restrict__ ndist,
                                              const int* __restrict__ nbid,
                                              const int* __restrict__ labels,
                                              const float* __restrict__ part,
                                              const float* __restrict__ Wbw,
                                              const float* __restrict__ Wsrc,
                                              float* __restrict__ out) {
    __shared__ float s_enc[BB * NF];         // 40
    __shared__ float s_dinv[BB * NF * MC];   // 320
    int tid = threadIdx.x;
    if (tid < BB * NF) {
        const float* p = part + tid * ENC_SLICES;
        float s = 0.f;
#pragma unroll
        for (int i = 0; i < ENC_SLICES; ++i) s += p[i];
        s_enc[tid] = s;
    }
    __syncthreads();
    for (int t = tid; t < BB * NF * MC; t += 256) {
        int b = t / (NF * MC);
        int r = t % (NF * MC);               // r = c*MC + m
        float z = 0.f;
#pragma unroll
        for (int c = 0; c < NF; ++c) z = fmaf(s_enc[b * NF + c], Wbw[r * NF + c], z);
        float sig = 1.f / (1.f + __expf(-z));
        const float lo = (float)(4.0 / 60.0 / 20.0);
        const float sc = (float)(1.0 / 60.0 - 4.0 / 60.0 / 20.0);
        float bwv = fmaf(sc, sig, lo) * MUF;
        s_dinv[t] = frcp(bwv * bwv);
    }
    __syncthreads();

    int g = blockIdx.x * 256 + tid;
    int j = g >> 1;
    if (j >= NN) return;
    int bh = (g & 1) << 1;                   // 0 or 2

    int lab = labels[j];
    float dA[NF], dB[NF];
#pragma unroll
    for (int c = 0; c < NF; ++c) {
        dA[c] = s_dinv[(bh)     * (NF * MC) + c * MC + lab];
        dB[c] = s_dinv[(bh + 1) * (NF * MC) + c * MC + lab];
    }

    const float4* dp = (const float4*)(ndist + (size_t)j * KK);
    float4 q0 = dp[0], q1 = dp[1], q2 = dp[2], q3 = dp[3];
    const int4* np = (const int4*)(nbid + (size_t)j * KK);
    int4 i0 = np[0], i1 = np[1], i2 = np[2], i3 = np[3];
    float nd[KK] = {q0.x, q0.y, q0.z, q0.w, q1.x, q1.y, q1.z, q1.w,
                    q2.x, q2.y, q2.z, q2.w, q3.x, q3.y, q3.z, q3.w};
    int nb[KK] = {i0.x, i0.y, i0.z, i0.w, i1.x, i1.y, i1.z, i1.w,
                  i2.x, i2.y, i2.z, i2.w, i3.x, i3.y, i3.z, i3.w};

    float wsA[NF], smA[NF], wsB[NF], smB[NF];
#pragma unroll
    for (int c = 0; c < NF; ++c) { wsA[c] = 0.f; smA[c] = 0.f; wsB[c] = 0.f; smB[c] = 0.f; }

#pragma unroll
    for (int k = 0; k < KK; ++k) {
        float d = nd[k];
        float dd = d * d;
        float bas[12];
        if (TR) {
            const float4* bp = (const float4*)(Wsrc + (size_t)(unsigned)nb[k] * 16);
            float4 b0 = bp[0], b1 = bp[1], b2 = bp[2];
            bas[0] = b0.x; bas[1] = b0.y; bas[2] = b0.z; bas[3] = b0.w;
            bas[4] = b1.x; bas[5] = b1.y; bas[6] = b1.z; bas[7] = b1.w;
            bas[8] = b2.x; bas[9] = b2.y; bas[10] = b2.z; bas[11] = b2.w;
        } else {
#pragma unroll
            for (int c = 0; c < NF; ++c) bas[c] = Wsrc[(size_t)c * NN + nb[k]];
        }
#pragma unroll
        for (int c = 0; c < NF; ++c) {
            float wA = fmaxf(fmaf(-dd, dA[c], 1.f), 0.f);
            wsA[c] += wA; smA[c] = fmaf(wA, bas[c], smA[c]);
            float wB = fmaxf(fmaf(-dd, dB[c], 1.f), 0.f);
            wsB[c] += wB; smB[c] = fmaf(wB, bas[c], smB[c]);
        }
    }

    float accA = 0.f, accB = 0.f;
#pragma unroll
    for (int c = 0; c < NF; ++c) {
        accA = fmaf(s_enc[bh * NF + c],       smA[c] * frcp(wsA[c]), accA);
        accB = fmaf(s_enc[(bh + 1) * NF + c], smB[c] * frcp(wsB[c]), accB);
    }
    out[(size_t)bh * NN + j]       = accA;
    out[(size_t)(bh + 1) * NN + j] = accB;
}

extern "C" void kernel_launch(void* const* d_in, const int* in_sizes, int n_in,
                              void* d_out, int out_size, void* d_ws, size_t ws_size,
                              hipStream_t stream) {
    const float* x      = (const float*)d_in[0];
    const float* Wenc   = (const float*)d_in[1];
    const float* Wdec   = (const float*)d_in[2];
    const float* Wbw    = (const float*)d_in[3];
    const float* ndist  = (const float*)d_in[4];
    const int*   nbid   = (const int*)d_in[5];
    const int*   labels = (const int*)d_in[6];
    float* out = (float*)d_out;

    float* part = (float*)d_ws;                       // 1280 floats
    float* Wt   = (float*)((char*)d_ws + 8192);       // N*16 floats (6.4 MB)
    size_t need = 8192 + (size_t)NN * 16 * sizeof(float);
    bool tr = (ws_size >= need);

    int main_blocks = (NN * 2 + 255) / 256;           // 782

    if (tr) {
        k_prep<true><<<ENC_BLOCKS + TR_BLOCKS, 256, 0, stream>>>(x, Wenc, Wdec, part, Wt);
        k_main<true><<<main_blocks, 256, 0, stream>>>(ndist, nbid, labels, part, Wbw, Wt, out);
    } else {
        k_prep<false><<<ENC_BLOCKS, 256, 0, stream>>>(x, Wenc, Wdec, part, nullptr);
        k_main<false><<<main_blocks, 256, 0, stream>>>(ndist, nbid, labels, part, Wbw, Wdec, out);
    }
}